// Round 3
// baseline (3891.927 us; speedup 1.0000x reference)
//
#include <hip/hip_runtime.h>
#include <hip/hip_bf16.h>
#include <math.h>

#define Nn 10000
#define Ee 160000
#define NPB 16            // dst nodes per block (625 * 16 = 10000 exactly)
#define NBLK 625
#define NKER 125
#define NBUCK (NBLK * NKER)

#define MPAD 10048        // 157 * 64   (lin2 M padding)
#define NPAD 6912         // 54 * 128   (lin2 N padding)
#define NCLS 6890

typedef short bf16x8 __attribute__((ext_vector_type(8)));
typedef float f32x4  __attribute__((ext_vector_type(4)));

__device__ inline unsigned short f2bf(float f) {
    unsigned u = __float_as_uint(f);
    return (unsigned short)((u + 0x7FFFu + ((u >> 16) & 1u)) >> 16);
}

// ---------------------------------------------------------------- basis
__global__ __launch_bounds__(256) void basis_kernel(const float* __restrict__ pseudo,
                                                    float* __restrict__ bw,
                                                    int* __restrict__ fl)
{
    int e = blockIdx.x * 256 + threadIdx.x;
    if (e >= Ee) return;
    float p0 = pseudo[e * 3 + 0] * 4.f;
    float p1 = pseudo[e * 3 + 1] * 4.f;
    float p2 = pseudo[e * 3 + 2] * 4.f;
    float f0 = floorf(p0), f1 = floorf(p1), f2 = floorf(p2);
    float fr0 = p0 - f0, fr1 = p1 - f1, fr2 = p2 - f2;
    int lo0 = (int)f0; lo0 = lo0 < 0 ? 0 : (lo0 > 4 ? 4 : lo0);
    int lo1 = (int)f1; lo1 = lo1 < 0 ? 0 : (lo1 > 4 ? 4 : lo1);
    int lo2 = (int)f2; lo2 = lo2 < 0 ? 0 : (lo2 > 4 ? 4 : lo2);
    int hi0 = lo0 + 1 > 4 ? 4 : lo0 + 1;
    int hi1 = lo1 + 1 > 4 ? 4 : lo1 + 1;
    int hi2 = lo2 + 1 > 4 ? 4 : lo2 + 1;
#pragma unroll
    for (int s = 0; s < 8; ++s) {
        int c0 = (s >> 2) & 1, c1 = (s >> 1) & 1, c2 = s & 1;
        float b = (c0 ? fr0 : 1.f - fr0) * (c1 ? fr1 : 1.f - fr1) * (c2 ? fr2 : 1.f - fr2);
        int f = (c0 ? hi0 : lo0) + 5 * (c1 ? hi1 : lo1) + 25 * (c2 ? hi2 : lo2);
        bw[e * 8 + s] = b;
        fl[e * 8 + s] = f;
    }
}

// ---------------------------------------------------------------- degree
__global__ __launch_bounds__(256) void deg_kernel(const int* __restrict__ dst, int* __restrict__ degi)
{
    int e = blockIdx.x * 256 + threadIdx.x;
    if (e >= Ee) return;
    atomicAdd(&degi[dst[e]], 1);
}

__global__ __launch_bounds__(256) void invdeg_kernel(const int* __restrict__ degi, float* __restrict__ invdeg)
{
    int n = blockIdx.x * 256 + threadIdx.x;
    if (n >= Nn) return;
    int d = degi[n];
    invdeg[n] = 1.f / (float)(d > 0 ? d : 1);
}

// ---------------------------------------------------------------- pair sort (counting sort by (dstblock, k))
__global__ __launch_bounds__(256) void hist_kernel(const int* __restrict__ dst, const int* __restrict__ fl,
                                                   int* __restrict__ hist)
{
    int t = blockIdx.x * 256 + threadIdx.x;
    if (t >= Ee * 8) return;
    int e = t >> 3;
    int key = (dst[e] >> 4) * NKER + fl[t];
    atomicAdd(&hist[key], 1);
}

__global__ __launch_bounds__(1024) void scan_kernel(const int* __restrict__ hist, int* __restrict__ boff)
{
    const int T = 1024;
    const int per = (NBUCK + T - 1) / T;
    int t = threadIdx.x;
    int beg = t * per;
    int end = beg + per; if (end > NBUCK) end = NBUCK;
    int s = 0;
    for (int i = beg; i < end && i < NBUCK; ++i) s += hist[i];
    __shared__ int tmp[1024];
    tmp[t] = s;
    __syncthreads();
    for (int o2 = 1; o2 < 1024; o2 <<= 1) {
        int v = (t >= o2) ? tmp[t - o2] : 0;
        __syncthreads();
        tmp[t] += v;
        __syncthreads();
    }
    int run = tmp[t] - s;
    for (int i = beg; i < end && i < NBUCK; ++i) { boff[i] = run; run += hist[i]; }
    if (t == T - 1) boff[NBUCK] = run;
}

__global__ __launch_bounds__(256) void fill_kernel(const int* __restrict__ srcA, const int* __restrict__ dstA,
                                                   const float* __restrict__ bw, const int* __restrict__ fl,
                                                   int* __restrict__ cursor, uint2* __restrict__ recs)
{
    int t = blockIdx.x * 256 + threadIdx.x;
    if (t >= Ee * 8) return;
    int e = t >> 3;
    int d = dstA[e];
    int key = (d >> 4) * NKER + fl[t];
    int pos = atomicAdd(&cursor[key], 1);
    unsigned meta = (unsigned)srcA[e] | ((unsigned)(d & 15) << 16);
    recs[pos] = make_uint2(meta, __float_as_uint(bw[t]));
}

// ---------------------------------------------------------------- weight transpose+convert: W[k][i][o] f32 -> Wt[k][o][i] bf16
__global__ __launch_bounds__(256) void wt_kernel(const float* __restrict__ W,
                                                 unsigned short* __restrict__ Wt,
                                                 int CIN, int COUT)
{
    __shared__ float t[32][33];
    int k = blockIdx.x;
    int nt = COUT / 32;
    int ti = (blockIdx.y / nt) * 32;   // input-feature tile
    int to = (blockIdx.y % nt) * 32;   // output-feature tile
    int tx = threadIdx.x & 31, ty = threadIdx.x >> 5;  // ty 0..7
    const float* Wk = W + (size_t)k * CIN * COUT;
    unsigned short* Wtk = Wt + (size_t)k * CIN * COUT;
#pragma unroll
    for (int q = 0; q < 4; ++q)
        t[ty + 8 * q][tx] = Wk[(size_t)(ti + ty + 8 * q) * COUT + to + tx];
    __syncthreads();
#pragma unroll
    for (int q = 0; q < 4; ++q)
        Wtk[(size_t)(to + ty + 8 * q) * CIN + ti + tx] = f2bf(t[tx][ty + 8 * q]);
}

// ---------------------------------------------------------------- conv layer 1 (CIN=1 -> COUT=32), VALU path, fused epilogue
__global__ __launch_bounds__(256) void conv1_kernel(const uint2* __restrict__ recs,
                                                    const int* __restrict__ boff,
                                                    const float* __restrict__ xin,   // [Nn]
                                                    const float* __restrict__ W1,    // [125][32]
                                                    const float* __restrict__ root1, // [32]
                                                    const float* __restrict__ b1,    // [32]
                                                    const float* __restrict__ invdeg,
                                                    float* __restrict__ out)         // [Nn][32]
{
    __shared__ float S[2][16];
    const int tid = threadIdx.x;
    const int o = tid & 31, rbase = tid >> 5;   // rbase 0..7
    const int blk = blockIdx.x;
    const int kb = blk * NKER;

    float acc0 = 0.f, acc1 = 0.f;
    if (tid < 32) S[tid >> 4][tid & 15] = 0.f;
    __syncthreads();
    int cur = 0;
    for (int k = 0; k < NKER; ++k) {
        int pb = boff[kb + k], pe = boff[kb + k + 1];
        if (pb == pe) continue;
        for (int p = pb + tid; p < pe; p += 256) {
            uint2 r = recs[p];
            int src = (int)(r.x & 0xFFFFu);
            int dl  = (int)(r.x >> 16);
            atomicAdd(&S[cur][dl], __uint_as_float(r.y) * xin[src]);
        }
        __syncthreads();
        float w1k = W1[k * 32 + o];
        acc0 += S[cur][rbase] * w1k;
        acc1 += S[cur][rbase + 8] * w1k;
        if (tid < 16) S[cur ^ 1][tid] = 0.f;
        __syncthreads();
        cur ^= 1;
    }
    int n0 = blk * NPB + rbase;
    int n1 = n0 + 8;
    float v0 = acc0 * invdeg[n0] + xin[n0] * root1[o] + b1[o];
    float v1 = acc1 * invdeg[n1] + xin[n1] * root1[o] + b1[o];
    out[(size_t)n0 * 32 + o] = v0 > 0.f ? v0 : expm1f(v0);
    out[(size_t)n1 * 32 + o] = v1 > 0.f ? v1 : expm1f(v1);
}

// ---------------------------------------------------------------- conv via MFMA (CIN in {32,64}, COUT=64), fused epilogue
// Per (block,k) bucket: gather S[dl][i] += wt*x[src][i] (LDS, fp32), then
// one 16x16x32 bf16 MFMA per wave (wave w = output cols w*16..w*16+15),
// accumulators live in registers across all 125 k. Root term = one more MFMA.
template <int CIN>
__global__ __launch_bounds__(256) void conv_mfma_kernel(const uint2* __restrict__ recs,
                                                        const int* __restrict__ boff,
                                                        const float* __restrict__ xin,          // [Nn][CIN]
                                                        const unsigned short* __restrict__ Wt,  // [125][64][CIN] bf16
                                                        const unsigned short* __restrict__ roott,// [64][CIN] bf16
                                                        const float* __restrict__ bias,         // [64]
                                                        const float* __restrict__ invdeg,
                                                        float* __restrict__ out)                // [Nn][64]
{
    constexpr int SROW = CIN + 4;    // +4 floats: break power-of-2 bank stride, keep 16B align
    __shared__ float S[2][16 * SROW];
    const int tid = threadIdx.x;
    const int lane = tid & 63, wid = tid >> 6;
    const int quad = lane >> 4, lq = lane & 15;
    const int blk = blockIdx.x;
    const int kb = blk * NKER;

    f32x4 acc = {0.f, 0.f, 0.f, 0.f};

    for (int idx = tid; idx < 2 * 16 * SROW; idx += 256) ((float*)S)[idx] = 0.f;
    __syncthreads();

    int cur = 0;
    for (int k = 0; k < NKER; ++k) {
        int pb = boff[kb + k], pe = boff[kb + k + 1];
        if (pb == pe) continue;
        float* Sc = S[cur];
        // ---- gather
        if (CIN == 64) {
            for (int p = pb + wid; p < pe; p += 4) {
                uint2 r = recs[p];
                int src = (int)(r.x & 0xFFFFu);
                int dl  = (int)(r.x >> 16);
                float wt = __uint_as_float(r.y);
                atomicAdd(&Sc[dl * SROW + lane], wt * xin[(size_t)src * CIN + lane]);
            }
        } else {
            int half = lane >> 5, feat = lane & 31;
            for (int p = pb + wid * 2 + half; p < pe; p += 8) {
                uint2 r = recs[p];
                int src = (int)(r.x & 0xFFFFu);
                int dl  = (int)(r.x >> 16);
                float wt = __uint_as_float(r.y);
                atomicAdd(&Sc[dl * SROW + feat], wt * xin[(size_t)src * CIN + feat]);
            }
        }
        __syncthreads();
        // ---- consume: S @ W[k] into register accumulators
        const unsigned short* Wk = Wt + (size_t)(k * 64 + wid * 16 + lq) * CIN;
#pragma unroll
        for (int kc = 0; kc < CIN; kc += 32) {
            const float* sp = &Sc[lq * SROW + kc + quad * 8];
            f32x4 a0 = *(const f32x4*)sp;
            f32x4 a1 = *(const f32x4*)(sp + 4);
            bf16x8 af;
            af[0] = (short)f2bf(a0[0]); af[1] = (short)f2bf(a0[1]);
            af[2] = (short)f2bf(a0[2]); af[3] = (short)f2bf(a0[3]);
            af[4] = (short)f2bf(a1[0]); af[5] = (short)f2bf(a1[1]);
            af[6] = (short)f2bf(a1[2]); af[7] = (short)f2bf(a1[3]);
            bf16x8 bfr = *(const bf16x8*)(Wk + kc + quad * 8);
            acc = __builtin_amdgcn_mfma_f32_16x16x32_bf16(af, bfr, acc, 0, 0, 0);
        }
        // ---- zero the other buffer for next k
        float* So = S[cur ^ 1];
        for (int idx = tid; idx < 16 * SROW; idx += 256) So[idx] = 0.f;
        __syncthreads();
        cur ^= 1;
    }

    // ---- scale edge aggregate by 1/deg (rows are all valid: NBLK*NPB == Nn)
#pragma unroll
    for (int r = 0; r < 4; ++r)
        acc[r] *= invdeg[blk * NPB + quad * 4 + r];

    // ---- root term: X_blk @ root via one more MFMA (stage X into the zeroed buffer)
    float* Sc = S[cur];
    for (int idx = tid; idx < 16 * CIN; idx += 256) {
        int row = idx / CIN, i = idx - row * CIN;
        Sc[row * SROW + i] = xin[(size_t)(blk * NPB + row) * CIN + i];
    }
    __syncthreads();
    const unsigned short* Rk = roott + (size_t)(wid * 16 + lq) * CIN;
#pragma unroll
    for (int kc = 0; kc < CIN; kc += 32) {
        const float* sp = &Sc[lq * SROW + kc + quad * 8];
        f32x4 a0 = *(const f32x4*)sp;
        f32x4 a1 = *(const f32x4*)(sp + 4);
        bf16x8 af;
        af[0] = (short)f2bf(a0[0]); af[1] = (short)f2bf(a0[1]);
        af[2] = (short)f2bf(a0[2]); af[3] = (short)f2bf(a0[3]);
        af[4] = (short)f2bf(a1[0]); af[5] = (short)f2bf(a1[1]);
        af[6] = (short)f2bf(a1[2]); af[7] = (short)f2bf(a1[3]);
        bf16x8 bfr = *(const bf16x8*)(Rk + kc + quad * 8);
        acc = __builtin_amdgcn_mfma_f32_16x16x32_bf16(af, bfr, acc, 0, 0, 0);
    }

    // ---- bias + ELU + store
    int col = wid * 16 + lq;
    float bb = bias[col];
#pragma unroll
    for (int r = 0; r < 4; ++r) {
        int n = blk * NPB + quad * 4 + r;
        float v = acc[r] + bb;
        out[(size_t)n * 64 + col] = v > 0.f ? v : expm1f(v);
    }
}

// ---------------------------------------------------------------- lin1: 64 -> 256, elu, emit bf16
__global__ __launch_bounds__(256) void lin1_kernel(const float* __restrict__ h,
                                                   const float* __restrict__ w1,
                                                   const float* __restrict__ b1,
                                                   __hip_bfloat16* __restrict__ out)
{
    int n = blockIdx.x;
    __shared__ float hl[64];
    if (threadIdx.x < 64) hl[threadIdx.x] = h[n * 64 + threadIdx.x];
    __syncthreads();
    int j = threadIdx.x;
    float a0 = b1[j], a1 = 0.f, a2 = 0.f, a3 = 0.f;
#pragma unroll
    for (int i = 0; i < 64; i += 4) {
        a0 += hl[i + 0] * w1[(i + 0) * 256 + j];
        a1 += hl[i + 1] * w1[(i + 1) * 256 + j];
        a2 += hl[i + 2] * w1[(i + 2) * 256 + j];
        a3 += hl[i + 3] * w1[(i + 3) * 256 + j];
    }
    float acc = (a0 + a1) + (a2 + a3);
    float v = acc > 0.f ? acc : expm1f(acc);
    out[(size_t)n * 256 + j] = __float2bfloat16(v);
}

// ---------------------------------------------------------------- w2 transpose + bf16: [256][6890] f32 -> [6912][256] bf16
__global__ __launch_bounds__(256) void w2t_kernel(const float* __restrict__ w2,
                                                  __hip_bfloat16* __restrict__ w2t)
{
    __shared__ float t[32][33];
    int n0 = blockIdx.x * 32;
    int k0 = blockIdx.y * 32;
    int tx = threadIdx.x & 31, ty = threadIdx.x >> 5;
#pragma unroll
    for (int q = 0; q < 4; ++q) {
        int k = k0 + ty + 8 * q, n = n0 + tx;
        t[ty + 8 * q][tx] = (n < NCLS) ? w2[(size_t)k * NCLS + n] : 0.f;
    }
    __syncthreads();
#pragma unroll
    for (int q = 0; q < 4; ++q) {
        int n = n0 + ty + 8 * q;
        w2t[(size_t)n * 256 + k0 + tx] = __float2bfloat16(t[tx][ty + 8 * q]);
    }
}

// ---------------------------------------------------------------- lin2 via MFMA: [10000,256] @ [256,6890] + b2
__global__ __launch_bounds__(256) void lin2_mfma_kernel(const __hip_bfloat16* __restrict__ hbf,
                                                        const __hip_bfloat16* __restrict__ w2t,
                                                        const float* __restrict__ b2,
                                                        float* __restrict__ out)
{
    const int tid  = threadIdx.x;
    const int lane = tid & 63, wid = tid >> 6;
    const int wr = wid & 1, wc = wid >> 1;
    const int quad = lane >> 4, lq = lane & 15;

    const int mbase = blockIdx.x * 64 + wr * 32;
    const int nbase = blockIdx.y * 128 + wc * 64;

    f32x4 acc[2][4];
#pragma unroll
    for (int i = 0; i < 2; ++i)
#pragma unroll
        for (int j = 0; j < 4; ++j) acc[i][j] = (f32x4){0.f, 0.f, 0.f, 0.f};

    const unsigned short* A = (const unsigned short*)hbf;
    const unsigned short* B = (const unsigned short*)w2t;

    for (int kc = 0; kc < 256; kc += 32) {
        bf16x8 af[2], bfr[4];
#pragma unroll
        for (int mt = 0; mt < 2; ++mt)
            af[mt] = *(const bf16x8*)(A + (size_t)(mbase + mt * 16 + lq) * 256 + kc + quad * 8);
#pragma unroll
        for (int nt = 0; nt < 4; ++nt)
            bfr[nt] = *(const bf16x8*)(B + (size_t)(nbase + nt * 16 + lq) * 256 + kc + quad * 8);
#pragma unroll
        for (int mt = 0; mt < 2; ++mt)
#pragma unroll
            for (int nt = 0; nt < 4; ++nt)
                acc[mt][nt] = __builtin_amdgcn_mfma_f32_16x16x32_bf16(af[mt], bfr[nt], acc[mt][nt], 0, 0, 0);
    }

#pragma unroll
    for (int nt = 0; nt < 4; ++nt) {
        int col = nbase + nt * 16 + lq;
        if (col >= NCLS) continue;
        float bb = b2[col];
#pragma unroll
        for (int mt = 0; mt < 2; ++mt) {
#pragma unroll
            for (int r = 0; r < 4; ++r) {
                int row = mbase + mt * 16 + quad * 4 + r;
                if (row < Nn) out[(size_t)row * NCLS + col] = acc[mt][nt][r] + bb;
            }
        }
    }
}

// ---------------------------------------------------------------- log_softmax (in place)
__global__ __launch_bounds__(1024) void lsm_kernel(float* __restrict__ out)
{
    int row = blockIdx.x;
    float* p = out + (size_t)row * NCLS;
    __shared__ float red[16];
    int tid = threadIdx.x, lane = tid & 63, wid = tid >> 6;

    float m = -3.4e38f;
    for (int jj = tid; jj < NCLS; jj += 1024) m = fmaxf(m, p[jj]);
#pragma unroll
    for (int off = 32; off > 0; off >>= 1) m = fmaxf(m, __shfl_down(m, off));
    if (lane == 0) red[wid] = m;
    __syncthreads();
    if (tid == 0) {
        float mm = red[0];
        for (int w = 1; w < 16; ++w) mm = fmaxf(mm, red[w]);
        red[0] = mm;
    }
    __syncthreads();
    m = red[0];
    __syncthreads();

    float s = 0.f;
    for (int jj = tid; jj < NCLS; jj += 1024) s += expf(p[jj] - m);
#pragma unroll
    for (int off = 32; off > 0; off >>= 1) s += __shfl_down(s, off);
    if (lane == 0) red[wid] = s;
    __syncthreads();
    if (tid == 0) {
        float ss = 0.f;
        for (int w = 1; w < 16; ++w) ss += red[w];
        red[0] += ss;
    }
    __syncthreads();
    float lse = m + logf(red[0]);
    for (int jj = tid; jj < NCLS; jj += 1024) p[jj] -= lse;
}

// ---------------------------------------------------------------- launch
extern "C" void kernel_launch(void* const* d_in, const int* in_sizes, int n_in,
                              void* d_out, int out_size, void* d_ws, size_t ws_size,
                              hipStream_t stream)
{
    const float* x      = (const float*)d_in[0];
    const int*   ei     = (const int*)d_in[1];
    const float* pseudo = (const float*)d_in[2];
    const float* W1     = (const float*)d_in[3];
    const float* root1  = (const float*)d_in[4];
    const float* b1     = (const float*)d_in[5];
    const float* W2     = (const float*)d_in[6];
    const float* root2  = (const float*)d_in[7];
    const float* b2     = (const float*)d_in[8];
    const float* Ws     = (const float*)d_in[9];
    const float* roots  = (const float*)d_in[10];
    const float* bs     = (const float*)d_in[11];
    const float* l1w    = (const float*)d_in[12];
    const float* l1b    = (const float*)d_in[13];
    const float* l2w    = (const float*)d_in[14];
    const float* l2b    = (const float*)d_in[15];
    float* out = (float*)d_out;

    const int* srcA = ei;
    const int* dstA = ei + Ee;

    char* base = (char*)d_ws;
    size_t off = 0;
    auto carve = [&](size_t bytes) -> void* {
        void* p = base + off;
        off += (bytes + 255) & ~(size_t)255;
        return p;
    };
    float* bw     = (float*)carve((size_t)Ee * 8 * 4);   // 5.12 MB, dead after fill -> reused for W2t/roots
    int*   fl     = (int*)carve((size_t)Ee * 8 * 4);     // 5.12 MB, dead after fill -> reused for Wst
    int*   hist   = (int*)carve((size_t)NBUCK * 4);
    int*   boff   = (int*)carve((size_t)(NBUCK + 1) * 4);
    int*   cursor = (int*)carve((size_t)NBUCK * 4);
    uint2* recs   = (uint2*)carve((size_t)Ee * 8 * 8);
    int*   degi   = (int*)carve((size_t)Nn * 4);
    float* invdeg = (float*)carve((size_t)Nn * 4);
    float* hA     = (float*)carve((size_t)Nn * 64 * 4);
    float* hB     = (float*)carve((size_t)Nn * 64 * 4);
    __hip_bfloat16* hbf = (__hip_bfloat16*)carve((size_t)MPAD * 256 * 2);
    __hip_bfloat16* w2t = (__hip_bfloat16*)carve((size_t)NPAD * 256 * 2);
    (void)ws_size; (void)n_in; (void)in_sizes; (void)out_size;

    // aliases into bw/fl regions (used only after fill_kernel has consumed bw/fl)
    unsigned short* W2t    = (unsigned short*)bw;                          // 125*32*64*2 = 512000 B
    unsigned short* root2t = (unsigned short*)((char*)bw + 524288);        // 32*64*2 = 4096 B
    unsigned short* rootst = (unsigned short*)((char*)bw + 532480);        // 4*64*64*2 = 32768 B
    unsigned short* Wst    = (unsigned short*)fl;                          // 4*125*64*64*2 = 4096000 B

    hipMemsetAsync(hist, 0, (size_t)NBUCK * 4, stream);
    hipMemsetAsync(degi, 0, (size_t)Nn * 4, stream);
    hipMemsetAsync(hbf, 0, (size_t)MPAD * 256 * 2, stream);

    basis_kernel<<<(Ee + 255) / 256, 256, 0, stream>>>(pseudo, bw, fl);
    deg_kernel<<<(Ee + 255) / 256, 256, 0, stream>>>(dstA, degi);
    invdeg_kernel<<<(Nn + 255) / 256, 256, 0, stream>>>(degi, invdeg);
    hist_kernel<<<(Ee * 8 + 255) / 256, 256, 0, stream>>>(dstA, fl, hist);
    scan_kernel<<<1, 1024, 0, stream>>>(hist, boff);
    hipMemcpyAsync(cursor, boff, (size_t)NBUCK * 4, hipMemcpyDeviceToDevice, stream);
    fill_kernel<<<(Ee * 8 + 255) / 256, 256, 0, stream>>>(srcA, dstA, bw, fl, cursor, recs);

    // weight transposes (bw/fl now dead; aliases safe in stream order)
    w2t_kernel<<<dim3((NPAD + 31) / 32, 8), 256, 0, stream>>>(l2w, w2t);
    wt_kernel<<<dim3(125, 2), 256, 0, stream>>>(W2, W2t, 32, 64);
    wt_kernel<<<dim3(1, 2), 256, 0, stream>>>(root2, root2t, 32, 64);
    for (int l = 0; l < 4; ++l) {
        wt_kernel<<<dim3(125, 4), 256, 0, stream>>>(Ws + (size_t)l * 125 * 64 * 64,
                                                    Wst + (size_t)l * 125 * 64 * 64, 64, 64);
        wt_kernel<<<dim3(1, 4), 256, 0, stream>>>(roots + (size_t)l * 64 * 64,
                                                  rootst + (size_t)l * 64 * 64, 64, 64);
    }

    // layer 1: 1 -> 32 (VALU)
    conv1_kernel<<<NBLK, 256, 0, stream>>>(recs, boff, x, W1, root1, b1, invdeg, hA);

    // layer 2: 32 -> 64 (MFMA)
    conv_mfma_kernel<32><<<NBLK, 256, 0, stream>>>(recs, boff, hA, W2t, root2t, b2, invdeg, hB);

    // layers 3..6: 64 -> 64 (MFMA)
    float* cin = hB;
    float* cot = hA;
    for (int l = 0; l < 4; ++l) {
        conv_mfma_kernel<64><<<NBLK, 256, 0, stream>>>(recs, boff, cin,
                                                       Wst + (size_t)l * 125 * 64 * 64,
                                                       rootst + (size_t)l * 64 * 64,
                                                       bs + (size_t)l * 64, invdeg, cot);
        float* t = cin; cin = cot; cot = t;
    }

    lin1_kernel<<<Nn, 256, 0, stream>>>(cin, l1w, l1b, hbf);
    lin2_mfma_kernel<<<dim3(MPAD / 64, NPAD / 128), 256, 0, stream>>>(hbf, w2t, l2b, out);
    lsm_kernel<<<Nn, 1024, 0, stream>>>(out);
}